// Round 7
// baseline (307.261 us; speedup 1.0000x reference)
//
#include <hip/hip_runtime.h>
#include <hip/hip_bf16.h>
#include <math.h>

// Problem constants (match reference)
constexpr int B = 4, S = 2048, E = 1024, H = 16, D = 64;
constexpr float NEGF = -1000000000.0f;
// scale folded into K pre-pass: 1/sqrt(64) * log2(e)  -> softmax uses exp2
constexpr float KSCALE = 0.125f * 1.44269504f;

typedef __attribute__((ext_vector_type(8))) short short8;   // 8 bf16 = 4 VGPRs
typedef __attribute__((ext_vector_type(16))) float f32x16;  // MFMA 32x32 C/D

// ---------------- helpers ----------------
// fast bf16 pair pack, round-half-up: 2 adds + 1 v_perm (vs ~14-instr RNE)
__device__ inline unsigned pk2(float a, float b) {
    unsigned ua = __builtin_bit_cast(unsigned, a) + 0x8000u;
    unsigned ub = __builtin_bit_cast(unsigned, b) + 0x8000u;
    // D.b01 = ua.b23 (lo16 = bf16(a)), D.b23 = ub.b23 (hi16 = bf16(b))
    return __builtin_amdgcn_perm(ub, ua, 0x07060302u);
}
__device__ inline void gl_lds16(const void* g, void* l) {
    __builtin_amdgcn_global_load_lds(
        (const __attribute__((address_space(1))) unsigned int*)g,
        (__attribute__((address_space(3))) unsigned int*)l, 16, 0, 0);
}

// ws layout (bytes):
//   Kws  [bh][s][72 bf16]          @ 0          18,874,368   (bf16, *KSCALE)
//   Vtws [bh][kt][64 d][72 bf16]   @ 18874368   18,874,368   (per-tile chunked)
//   Mby  [b][q][tile][64 bytes]    @ 37748736   16,777,216   (0x00/0xFF, permuted)
// Mby permutation within a 64-byte (b,q,tile) row: 4-key group g (=key/4)
// lands at dword index (g&1)*8 + (g>>1)  -> h6 half reads 32 B contiguous.
constexpr size_t WS_K  = 0;
constexpr size_t WS_VT = 18874368;
constexpr size_t WS_MB = 37748736;
constexpr size_t WS_NEED = 54525952;

// ---------------- fused pre-pass: K-cvt, V-transpose, mask-bytes ------------
__global__ void prep_all(const float* __restrict__ K, const float* __restrict__ V,
                         const int* __restrict__ M, char* __restrict__ ws) {
    __shared__ float Vf[64][69];
    const int bid = blockIdx.x, tid = threadIdx.x;

    // ---- K convert: dst row = (b*H+h)*S + s, 72 bf16/row ----
    {
        int g = bid * 256 + tid;                  // 524288 threads total
        int rowd = g >> 2, qtr = g & 3;
        int b = rowd >> 15, h = (rowd >> 11) & 15, s = rowd & 2047;
        const float* p = K + ((size_t)(b * S + s)) * E + h * 64 + qtr * 16;
        float4 v0 = *(const float4*)(p + 0),  v1 = *(const float4*)(p + 4);
        float4 v2 = *(const float4*)(p + 8),  v3 = *(const float4*)(p + 12);
        uint4 o0, o1;
        o0.x = pk2(v0.x * KSCALE, v0.y * KSCALE); o0.y = pk2(v0.z * KSCALE, v0.w * KSCALE);
        o0.z = pk2(v1.x * KSCALE, v1.y * KSCALE); o0.w = pk2(v1.z * KSCALE, v1.w * KSCALE);
        o1.x = pk2(v2.x * KSCALE, v2.y * KSCALE); o1.y = pk2(v2.z * KSCALE, v2.w * KSCALE);
        o1.z = pk2(v3.x * KSCALE, v3.y * KSCALE); o1.w = pk2(v3.z * KSCALE, v3.w * KSCALE);
        char* d = ws + WS_K + (size_t)rowd * 144 + qtr * 32;
        *(uint4*)d = o0; *(uint4*)(d + 16) = o1;
        if (qtr == 3) {                           // pad cols 64..71 -> full rows
            uint4 z; z.x = z.y = z.z = z.w = 0;
            *(uint4*)(d + 32) = z;
        }
    }

    // ---- V transpose: tile (bh,kt) -> 64 d-rows x 72 bf16 ----
    {
        int bh = bid >> 5, kt = bid & 31;
        int b = bh >> 4, h = bh & 15;
        {
            int r = tid >> 2, c4 = (tid & 3) * 16;
            const float* p = V + ((size_t)(b * S + kt * 64 + r)) * E + h * 64 + c4;
            float4 a = *(const float4*)(p + 0), bb = *(const float4*)(p + 4);
            float4 c = *(const float4*)(p + 8), dd = *(const float4*)(p + 12);
            *(float4*)&Vf[r][c4 + 0] = a;  *(float4*)&Vf[r][c4 + 4] = bb;
            *(float4*)&Vf[r][c4 + 8] = c;  *(float4*)&Vf[r][c4 + 12] = dd;
        }
        __syncthreads();
        int d = tid >> 2, sq = (tid & 3) * 16;
        float v[16];
#pragma unroll
        for (int i = 0; i < 16; ++i) v[i] = Vf[sq + i][d];
        uint4 o0, o1;
        o0.x = pk2(v[0], v[1]);   o0.y = pk2(v[2], v[3]);
        o0.z = pk2(v[4], v[5]);   o0.w = pk2(v[6], v[7]);
        o1.x = pk2(v[8], v[9]);   o1.y = pk2(v[10], v[11]);
        o1.z = pk2(v[12], v[13]); o1.w = pk2(v[14], v[15]);
        char* o = ws + WS_VT + ((size_t)(bh * 32 + kt)) * 9216 + d * 144 + sq * 2;
        *(uint4*)o = o0; *(uint4*)(o + 16) = o1;
        if (sq == 48) {
            uint4 z; z.x = z.y = z.z = z.w = 0;
            *(uint4*)(o + 32) = z;
        }
    }

    // ---- mask -> permuted byte-mask (0x00/0xFF per key) ----
    {
        unsigned* Mb = (unsigned*)(ws + WS_MB);
        const int t = bid * 256 + tid;
#pragma unroll
        for (int it = 0; it < 8; ++it) {
            int gidx = it * 524288 + t;           // 4-key group index, coalesced
            int4 mv = *((const int4*)M + gidx);
            unsigned d = (mv.x ? 0xFFu : 0u) | (mv.y ? 0xFF00u : 0u)
                       | (mv.z ? 0xFF0000u : 0u) | (mv.w ? 0xFF000000u : 0u);
            int row = gidx >> 4, g = gidx & 15;
            Mb[row * 16 + (g & 1) * 8 + (g >> 1)] = d;
        }
    }
}

// ---------------- main: fused attention, transposed-world MFMA ----------------
// Wave owns 32 q. Grid 1024 blocks; 4 blocks/CU, 16 waves/CU.
// Mask regs ROTATE one tile ahead: issued in tile ti, consumed in tile ti+1
// AFTER the barrier (which drains vmcnt per-wave anyway) -> zero mid-compute
// VMEM waits; the K/V prefetch is never drained early (r6's hidden stall).
__global__ __launch_bounds__(256, 4)
void fa_mfma(const float* __restrict__ Q, const char* __restrict__ ws,
             float* __restrict__ O) {
    __shared__ char smem[36864];              // 2 x (Ks 9216 | Vt 9216)
    const int tid = threadIdx.x;
    const int w = tid >> 6, lane = tid & 63;
    const int L5 = lane & 31, h6 = lane >> 5;
    const int h = blockIdx.x & 15, b = (blockIdx.x >> 4) & 3, qt = blockIdx.x >> 6;
    const int bh = b * 16 + h;
    const int q0w = qt * 128 + w * 32;        // wave's 32-q base

    const char* Kws  = ws + WS_K;
    const char* Vtws = ws + WS_VT;
    const int qA = q0w + L5;
    // per-lane mask row base: ((b*S+qA)*32 + ti)*64 bytes, h6 half = 32 B
    const char* mrow = ws + WS_MB + ((size_t)(b * S + qA)) * 2048 + h6 * 32;

    // ---- Q fragments: direct fp32 global loads + in-reg cvt ----
    short8 qf[4];
#pragma unroll
    for (int ks = 0; ks < 4; ++ks) {
        const float* qp = Q + ((size_t)(b * S + qA)) * E + h * 64 + ks * 16 + h6 * 8;
        float4 a = *(const float4*)qp;
        float4 c = *(const float4*)(qp + 4);
        uint4 u;
        u.x = pk2(a.x, a.y); u.y = pk2(a.z, a.w);
        u.z = pk2(c.x, c.y); u.w = pk2(c.z, c.w);
        qf[ks] = *(short8*)&u;
    }

    f32x16 acc[2];
#pragma unroll
    for (int mb = 0; mb < 2; ++mb) acc[mb] = (f32x16)0.0f;
    float l0 = 0.0f;

    // preload tile-0 masks (drained by the first barrier, not mid-compute)
    uint4 mnl = *(const uint4*)(mrow);
    uint4 mnh = *(const uint4*)(mrow + 16);

    // stage tile 0 into buf 0
    {
        const char* ksrc = Kws + ((size_t)bh * S) * 144;
        const char* vsrc = Vtws + ((size_t)bh * 32) * 9216;
#pragma unroll
        for (int c = 0; c < 5; ++c) {
            int idx = c * 4 + w;
            if (idx < 18) {
                int off = idx * 1024;
                const char* g = (off < 9216) ? (ksrc + off) : (vsrc + off - 9216);
                gl_lds16(g + lane * 16, smem + off);
            }
        }
    }

    for (int ti = 0; ti < 32; ++ti) {
        __syncthreads();   // tile ti + its masks visible; buf (ti+1)&1 free

        // rotate mask regs: current tile's masks were loaded last iteration
        const uint4 mcl = mnl, mch = mnh;
        const unsigned mdw[8] = {mcl.x, mcl.y, mcl.z, mcl.w,
                                 mch.x, mch.y, mch.z, mch.w};
        // issue NEXT tile's mask loads now; consumed only after next barrier
        {
            const int tn = (ti + 1 < 32) ? (ti + 1) : 31;   // clamp: no OOB
            mnl = *(const uint4*)(mrow + tn * 64);
            mnh = *(const uint4*)(mrow + tn * 64 + 16);
        }

        if (ti + 1 < 32) {  // prefetch tile ti+1 into other buffer
            const char* ksrc = Kws + ((size_t)bh * S + (ti + 1) * 64) * 144;
            const char* vsrc = Vtws + ((size_t)(bh * 32 + ti + 1)) * 9216;
            char* dst = smem + ((ti + 1) & 1) * 18432;
#pragma unroll
            for (int c = 0; c < 5; ++c) {
                int idx = c * 4 + w;
                if (idx < 18) {
                    int off = idx * 1024;
                    const char* g = (off < 9216) ? (ksrc + off) : (vsrc + off - 9216);
                    gl_lds16(g + lane * 16, dst + off);
                }
            }
        }

        const char* Ks = smem + (ti & 1) * 18432;
        const char* Vt = Ks + 9216;

#pragma unroll
        for (int mbK = 0; mbK < 2; ++mbK) {
            // ---- scores for 32 keys x 32 q ----
            short8 kf[4];
#pragma unroll
            for (int ks = 0; ks < 4; ++ks)
                kf[ks] = *(const short8*)(Ks + (mbK * 32 + L5) * 144 + ks * 32 + h6 * 16);

            f32x16 s = (f32x16)0.0f;
#pragma unroll
            for (int ks = 0; ks < 4; ++ks)
                s = __builtin_amdgcn_mfma_f32_32x32x16_bf16(kf[ks], qf[ks], s, 0, 0, 0);

            // ---- softmax: exp2 -> pack -> byte-mask AND -> rowsum ----
            float lacc = 0.0f;
            unsigned pd[8];
#pragma unroll
            for (int i = 0; i < 8; ++i) {
                float e0 = __builtin_amdgcn_exp2f(s[2 * i]);
                float e1 = __builtin_amdgcn_exp2f(s[2 * i + 1]);
                unsigned pm = pk2(e0, e1);
                const unsigned mv = mdw[mbK * 4 + (i >> 1)];
                const unsigned am = __builtin_amdgcn_perm(
                    mv, mv, (i & 1) ? 0x03030202u : 0x01010000u);
                pm &= am;                          // masked key -> bf16 +0.0
                pd[i] = pm;
                float lo = __builtin_bit_cast(float, pm << 16);
                float hi = __builtin_bit_cast(float, pm & 0xFFFF0000u);
                lacc += lo + hi;                   // l consistent with bf16 P
            }
            l0 += lacc;

            // ---- build P^T B-fragments via lane^32 exchange ----
            short8 pf[2];
#pragma unroll
            for (int sub = 0; sub < 2; ++sub) {
                const unsigned dA = pd[4 * sub + 0], dB = pd[4 * sub + 1];
                const unsigned dC = pd[4 * sub + 2], dD = pd[4 * sub + 3];
                const unsigned t0 = h6 ? dA : dC;
                const unsigned t1 = h6 ? dB : dD;
                const unsigned r0 = (unsigned)__shfl_xor((int)t0, 32, 64);
                const unsigned r1 = (unsigned)__shfl_xor((int)t1, 32, 64);
                uint4 u;
                u.x = h6 ? r0 : dA;  u.y = h6 ? r1 : dB;
                u.z = h6 ? dC : r0;  u.w = h6 ? dD : r1;
                pf[sub] = *(short8*)&u;
            }

            // ---- O^T += V^T * P^T for this key block ----
#pragma unroll
            for (int mbV = 0; mbV < 2; ++mbV) {
#pragma unroll
                for (int sub = 0; sub < 2; ++sub) {
                    short8 vf = *(const short8*)(Vt + (mbV * 32 + L5) * 144
                                                 + (mbK * 2 + sub) * 32 + h6 * 16);
                    acc[mbV] = __builtin_amdgcn_mfma_f32_32x32x16_bf16(
                        vf, pf[sub], acc[mbV], 0, 0, 0);
                }
            }
        }
    }

    // ---- epilogue: l-reduce across h6 halves, LDS transpose, store ----
    l0 += __shfl_xor(l0, 32, 64);
    const float inv = 1.0f / l0;
    __syncthreads();                       // done with smem everywhere
    float* ep = (float*)(smem + w * 4608); // wave-private 32q x 36dw
#pragma unroll
    for (int mb = 0; mb < 2; ++mb) {
#pragma unroll
        for (int r = 0; r < 16; ++r) {
            const int d = (r & 3) + 8 * (r >> 2) + h6 * 4;
            ep[L5 * 36 + d] = acc[mb][r] * inv;
        }
        __builtin_amdgcn_s_waitcnt(0xc07f);   // lgkmcnt(0): writes done
        const int row = lane >> 1, c = (lane & 1) * 16;
#pragma unroll
        for (int i = 0; i < 4; ++i) {
            float4 t = *(const float4*)&ep[row * 36 + c + 4 * i];
            *(float4*)(O + ((size_t)(b * S + q0w + row)) * E
                         + h * 64 + mb * 32 + c + 4 * i) = t;
        }
        __builtin_amdgcn_s_waitcnt(0xc07f);   // reads done before overwrite
    }
}

// ---------------- fallback (round-1 fp32 kernel, known-correct) ----------------
constexpr int QT = 64, KT = 64, LD = D + 4;
constexpr float SCALE = 0.125f;
__global__ __launch_bounds__(256, 3)
void fa_fp32(const float* __restrict__ Q, const float* __restrict__ K,
             const float* __restrict__ V, const int* __restrict__ M,
             float* __restrict__ Out)
{
    __shared__ float Qs[QT][LD];
    __shared__ float Vs[KT][LD];
    __shared__ float KPs[KT][LD];
    const int tid = threadIdx.x, tx = tid & 15, ty = tid >> 4;
    const int bid = blockIdx.x;
    const int h = bid % H, b = (bid / H) % B, qt = bid / (H * B);
    const int q0 = qt * QT;
    {
        const int col = tx * 4;
#pragma unroll
        for (int i = 0; i < 4; ++i) {
            const int row = ty + i * 16;
            *(float4*)&Qs[row][col] = *(const float4*)&Q[((size_t)(b * S + q0 + row)) * E + h * D + col];
        }
    }
    const int qr0 = ty * 4, d0 = tx * 4;
    float acc[4][4] = {};
    float m_i[4], l_i[4];
#pragma unroll
    for (int j = 0; j < 4; ++j) { m_i[j] = -INFINITY; l_i[j] = 0.0f; }
    for (int kt = 0; kt < S; kt += KT) {
        __syncthreads();
        {
            const int col = tx * 4;
#pragma unroll
            for (int i = 0; i < 4; ++i) {
                const int row = ty + i * 16;
                const size_t g = ((size_t)(b * S + kt + row)) * E + h * D + col;
                *(float4*)&KPs[row][col] = *(const float4*)&K[g];
                *(float4*)&Vs[row][col] = *(const float4*)&V[g];
            }
        }
        __syncthreads();
        float s[4][4] = {};
#pragma unroll
        for (int d = 0; d < D; d += 4) {
            float4 a[4], bb[4];
#pragma unroll
            for (int j = 0; j < 4; ++j) a[j] = *(const float4*)&Qs[qr0 + j][d];
#pragma unroll
            for (int i = 0; i < 4; ++i) bb[i] = *(const float4*)&KPs[tx + 16 * i][d];
#pragma unroll
            for (int j = 0; j < 4; ++j)
#pragma unroll
                for (int i = 0; i < 4; ++i)
                    s[j][i] += a[j].x * bb[i].x + a[j].y * bb[i].y + a[j].z * bb[i].z + a[j].w * bb[i].w;
        }
#pragma unroll
        for (int j = 0; j < 4; ++j) {
            const int* mrow = &M[((size_t)b * S + (q0 + qr0 + j)) * S + kt];
#pragma unroll
            for (int i = 0; i < 4; ++i) {
                const int mk = mrow[tx + 16 * i];
                s[j][i] = mk ? s[j][i] * SCALE : NEGF;
            }
        }
#pragma unroll
        for (int j = 0; j < 4; ++j) {
            float tm = fmaxf(fmaxf(s[j][0], s[j][1]), fmaxf(s[j][2], s[j][3]));
#pragma unroll
            for (int off = 8; off; off >>= 1) tm = fmaxf(tm, __shfl_xor(tm, off, 16));
            const float nm = fmaxf(m_i[j], tm);
            const float alpha = __expf(m_i[j] - nm);
            m_i[j] = nm;
            float rs = 0.0f;
#pragma unroll
            for (int i = 0; i < 4; ++i) { const float p = __expf(s[j][i] - nm); s[j][i] = p; rs += p; }
#pragma unroll
            for (int off = 8; off; off >>= 1) rs += __shfl_xor(rs, off, 16);
            l_i[j] = l_i[j] * alpha + rs;
#pragma unroll
            for (int dd = 0; dd < 4; ++dd) acc[j][dd] *= alpha;
        }
        __syncthreads();
#pragma unroll
        for (int j = 0; j < 4; ++j)
#pragma unroll
            for (int i = 0; i < 4; ++i) KPs[qr0 + j][tx + 16 * i] = s[j][i];
        __syncthreads();
#pragma unroll 4
        for (int kk = 0; kk < KT; kk += 4) {
            float4 p[4], vv[4];
#pragma unroll
            for (int j = 0; j < 4; ++j) p[j] = *(const float4*)&KPs[qr0 + j][kk];
#pragma unroll
            for (int u = 0; u < 4; ++u) vv[u] = *(const float4*)&Vs[kk + u][d0];
#pragma unroll
            for (int j = 0; j < 4; ++j) {
                acc[j][0] += p[j].x * vv[0].x + p[j].y * vv[1].x + p[j].z * vv[2].x + p[j].w * vv[3].x;
                acc[j][1] += p[j].x * vv[0].y + p[j].y * vv[1].y + p[j].z * vv[2].y + p[j].w * vv[3].y;
                acc[j][2] += p[j].x * vv[0].z + p[j].y * vv[1].z + p[j].z * vv[2].z + p[j].w * vv[3].z;
                acc[j][3] += p[j].x * vv[0].w + p[j].y * vv[1].w + p[j].z * vv[2].w + p[j].w * vv[3].w;
            }
        }
    }
#pragma unroll
    for (int j = 0; j < 4; ++j) {
        const float iv = 1.0f / l_i[j];
        float4 r;
        r.x = acc[j][0] * iv; r.y = acc[j][1] * iv; r.z = acc[j][2] * iv; r.w = acc[j][3] * iv;
        *(float4*)&Out[((size_t)(b * S + q0 + qr0 + j)) * E + h * D + d0] = r;
    }
}

extern "C" void kernel_launch(void* const* d_in, const int* in_sizes, int n_in,
                              void* d_out, int out_size, void* d_ws, size_t ws_size,
                              hipStream_t stream) {
    (void)in_sizes; (void)n_in; (void)out_size;
    const float* q = (const float*)d_in[0];
    const float* k = (const float*)d_in[1];
    const float* v = (const float*)d_in[2];
    const int*   m = (const int*)d_in[3];
    float* out = (float*)d_out;

    if (ws_size >= WS_NEED) {
        char* ws = (char*)d_ws;
        prep_all<<<2048, 256, 0, stream>>>(k, v, m, ws);
        fa_mfma<<<1024, 256, 0, stream>>>(q, ws, out);
    } else {
        fa_fp32<<<B * H * (S / QT), 256, 0, stream>>>(q, k, v, m, out);
    }
}

// Round 8
// 291.007 us; speedup vs baseline: 1.0559x; 1.0559x over previous
//
#include <hip/hip_runtime.h>
#include <hip/hip_bf16.h>
#include <math.h>

// Problem constants (match reference)
constexpr int B = 4, S = 2048, E = 1024, H = 16, D = 64;
constexpr float NEGF = -1000000000.0f;
// scale folded into K pre-pass: 1/sqrt(64) * log2(e)  -> softmax uses exp2
constexpr float KSCALE = 0.125f * 1.44269504f;

typedef __attribute__((ext_vector_type(8))) short short8;   // 8 bf16 = 4 VGPRs
typedef __attribute__((ext_vector_type(16))) float f32x16;  // MFMA 32x32 C/D

// ---------------- helpers ----------------
// fast bf16 pair pack, round-half-up: 2 adds + 1 v_perm (vs ~14-instr RNE)
__device__ inline unsigned pk2(float a, float b) {
    unsigned ua = __builtin_bit_cast(unsigned, a) + 0x8000u;
    unsigned ub = __builtin_bit_cast(unsigned, b) + 0x8000u;
    return __builtin_amdgcn_perm(ub, ua, 0x07060302u);
}
__device__ inline void gl_lds16(const void* g, void* l) {
    __builtin_amdgcn_global_load_lds(
        (const __attribute__((address_space(1))) unsigned int*)g,
        (__attribute__((address_space(3))) unsigned int*)l, 16, 0, 0);
}

// ws layout (bytes):
//   Kws  [bh][s][72 bf16]          @ 0          18,874,368   (bf16, *KSCALE)
//   Vtws [bh][kt][64 d][72 bf16]   @ 18874368   18,874,368   (per-tile chunked)
//   Mby  [b][q][tile][64 bytes]    @ 37748736   16,777,216   (0x00/0xFF, permuted)
constexpr size_t WS_K  = 0;
constexpr size_t WS_VT = 18874368;
constexpr size_t WS_MB = 37748736;
constexpr size_t WS_NEED = 54525952;

// ---------------- fused pre-pass: K-cvt, V-transpose, mask-bytes ------------
__global__ void prep_all(const float* __restrict__ K, const float* __restrict__ V,
                         const int* __restrict__ M, char* __restrict__ ws) {
    __shared__ float Vf[64][69];
    const int bid = blockIdx.x, tid = threadIdx.x;

    // ---- K convert: dst row = (b*H+h)*S + s, 72 bf16/row ----
    {
        int g = bid * 256 + tid;
        int rowd = g >> 2, qtr = g & 3;
        int b = rowd >> 15, h = (rowd >> 11) & 15, s = rowd & 2047;
        const float* p = K + ((size_t)(b * S + s)) * E + h * 64 + qtr * 16;
        float4 v0 = *(const float4*)(p + 0),  v1 = *(const float4*)(p + 4);
        float4 v2 = *(const float4*)(p + 8),  v3 = *(const float4*)(p + 12);
        uint4 o0, o1;
        o0.x = pk2(v0.x * KSCALE, v0.y * KSCALE); o0.y = pk2(v0.z * KSCALE, v0.w * KSCALE);
        o0.z = pk2(v1.x * KSCALE, v1.y * KSCALE); o0.w = pk2(v1.z * KSCALE, v1.w * KSCALE);
        o1.x = pk2(v2.x * KSCALE, v2.y * KSCALE); o1.y = pk2(v2.z * KSCALE, v2.w * KSCALE);
        o1.z = pk2(v3.x * KSCALE, v3.y * KSCALE); o1.w = pk2(v3.z * KSCALE, v3.w * KSCALE);
        char* d = ws + WS_K + (size_t)rowd * 144 + qtr * 32;
        *(uint4*)d = o0; *(uint4*)(d + 16) = o1;
        if (qtr == 3) {
            uint4 z; z.x = z.y = z.z = z.w = 0;
            *(uint4*)(d + 32) = z;
        }
    }

    // ---- V transpose: tile (bh,kt) -> 64 d-rows x 72 bf16 ----
    {
        int bh = bid >> 5, kt = bid & 31;
        int b = bh >> 4, h = bh & 15;
        {
            int r = tid >> 2, c4 = (tid & 3) * 16;
            const float* p = V + ((size_t)(b * S + kt * 64 + r)) * E + h * 64 + c4;
            float4 a = *(const float4*)(p + 0), bb = *(const float4*)(p + 4);
            float4 c = *(const float4*)(p + 8), dd = *(const float4*)(p + 12);
            *(float4*)&Vf[r][c4 + 0] = a;  *(float4*)&Vf[r][c4 + 4] = bb;
            *(float4*)&Vf[r][c4 + 8] = c;  *(float4*)&Vf[r][c4 + 12] = dd;
        }
        __syncthreads();
        int d = tid >> 2, sq = (tid & 3) * 16;
        float v[16];
#pragma unroll
        for (int i = 0; i < 16; ++i) v[i] = Vf[sq + i][d];
        uint4 o0, o1;
        o0.x = pk2(v[0], v[1]);   o0.y = pk2(v[2], v[3]);
        o0.z = pk2(v[4], v[5]);   o0.w = pk2(v[6], v[7]);
        o1.x = pk2(v[8], v[9]);   o1.y = pk2(v[10], v[11]);
        o1.z = pk2(v[12], v[13]); o1.w = pk2(v[14], v[15]);
        char* o = ws + WS_VT + ((size_t)(bh * 32 + kt)) * 9216 + d * 144 + sq * 2;
        *(uint4*)o = o0; *(uint4*)(o + 16) = o1;
        if (sq == 48) {
            uint4 z; z.x = z.y = z.z = z.w = 0;
            *(uint4*)(o + 32) = z;
        }
    }

    // ---- mask -> permuted byte-mask (0x00/0xFF per key) ----
    {
        unsigned* Mb = (unsigned*)(ws + WS_MB);
        const int t = bid * 256 + tid;
#pragma unroll
        for (int it = 0; it < 8; ++it) {
            int gidx = it * 524288 + t;
            int4 mv = *((const int4*)M + gidx);
            unsigned d = (mv.x ? 0xFFu : 0u) | (mv.y ? 0xFF00u : 0u)
                       | (mv.z ? 0xFF0000u : 0u) | (mv.w ? 0xFF000000u : 0u);
            int row = gidx >> 4, g = gidx & 15;
            Mb[row * 16 + (g & 1) * 8 + (g >> 1)] = d;
        }
    }
}

// ---------------- main: r2 structure + cheap softmax ----------------
// Block: 256 thr = 4 waves; wave owns 64 q (2 nb-streams of 32 -> ILP).
// Single shared K/V buffer, dedicated 2-barrier staging phase per tile
// (empirically beat dbuf: r2=119 vs r4..r7=139-147). P goes through
// wave-private LDS (ds_write_b64 burst + one lgkmcnt), NOT shuffles.
__global__ __launch_bounds__(256, 2)
void fa_mfma(const float* __restrict__ Q, const char* __restrict__ ws,
             float* __restrict__ O) {
    // LDS: Ks [0,9216) | Vt [9216,18432) | Ps 4 x 9216 per wave [18432,55296)
    __shared__ char smem[55296];
    const int tid = threadIdx.x;
    const int w = tid >> 6, lane = tid & 63;
    const int L5 = lane & 31, h6 = lane >> 5;
    const int h = blockIdx.x & 15, b = (blockIdx.x >> 4) & 3, qt = blockIdx.x >> 6;
    const int bh = b * 16 + h;
    const int q0w = qt * 256 + w * 64;            // wave's q base
    char* const Ps = smem + 18432 + w * 9216;     // wave-private

    const char* Kws  = ws + WS_K;
    const char* Vtws = ws + WS_VT;
    const int qA = q0w + L5, qB = qA + 32;
    const char* mrowA = ws + WS_MB + ((size_t)(b * S + qA)) * 2048 + h6 * 32;
    const char* mrowB = ws + WS_MB + ((size_t)(b * S + qB)) * 2048 + h6 * 32;

    // ---- Q fragments: direct fp32 global loads + in-reg cvt ----
    short8 qf[2][4];
#pragma unroll
    for (int nb = 0; nb < 2; ++nb)
#pragma unroll
        for (int ks = 0; ks < 4; ++ks) {
            const float* qp = Q + ((size_t)(b * S + q0w + nb * 32 + L5)) * E
                                + h * 64 + ks * 16 + h6 * 8;
            float4 a = *(const float4*)qp;
            float4 c = *(const float4*)(qp + 4);
            uint4 u;
            u.x = pk2(a.x, a.y); u.y = pk2(a.z, a.w);
            u.z = pk2(c.x, c.y); u.w = pk2(c.z, c.w);
            qf[nb][ks] = *(short8*)&u;
        }

    f32x16 acc[2][2];
#pragma unroll
    for (int mb = 0; mb < 2; ++mb)
#pragma unroll
        for (int nb = 0; nb < 2; ++nb) acc[mb][nb] = (f32x16)0.0f;
    float l0 = 0.0f, l1 = 0.0f;

    for (int ti = 0; ti < 32; ++ti) {
        // mask bytes for this tile (issued pre-barrier, drained by barrier B)
        const uint4 mAl = *(const uint4*)(mrowA + ti * 64);
        const uint4 mAh = *(const uint4*)(mrowA + ti * 64 + 16);
        const uint4 mBl = *(const uint4*)(mrowB + ti * 64);
        const uint4 mBh = *(const uint4*)(mrowB + ti * 64 + 16);
        const unsigned mdwA[8] = {mAl.x, mAl.y, mAl.z, mAl.w, mAh.x, mAh.y, mAh.z, mAh.w};
        const unsigned mdwB[8] = {mBl.x, mBl.y, mBl.z, mBl.w, mBh.x, mBh.y, mBh.z, mBh.w};

        __syncthreads();   // A: previous tile's compute done; buffer free
        {   // stage K tile (9216) + Vt tile (9216): pure linear async copy
            const char* ksrc = Kws + ((size_t)bh * S + ti * 64) * 144;
            const char* vsrc = Vtws + ((size_t)(bh * 32 + ti)) * 9216;
#pragma unroll
            for (int c = 0; c < 5; ++c) {
                int idx = c * 4 + w;
                if (idx < 18) {
                    int off = idx * 1024;
                    const char* g = (off < 9216) ? (ksrc + off) : (vsrc + off - 9216);
                    gl_lds16(g + lane * 16, smem + off);
                }
            }
        }
        __syncthreads();   // B: tiles visible (drains vmcnt)

        // ---- scores + softmax + P store ----
#pragma unroll
        for (int mbK = 0; mbK < 2; ++mbK) {
            short8 kf[4];
#pragma unroll
            for (int ks = 0; ks < 4; ++ks)
                kf[ks] = *(const short8*)(smem + (mbK * 32 + L5) * 144 + ks * 32 + h6 * 16);
#pragma unroll
            for (int nb = 0; nb < 2; ++nb) {
                f32x16 s = (f32x16)0.0f;
#pragma unroll
                for (int ks = 0; ks < 4; ++ks)
                    s = __builtin_amdgcn_mfma_f32_32x32x16_bf16(kf[ks], qf[nb][ks], s, 0, 0, 0);

                const unsigned* mdw = nb ? mdwB : mdwA;
                float lacc = 0.0f;
                unsigned pd[8];
#pragma unroll
                for (int i = 0; i < 8; ++i) {
                    float e0 = __builtin_amdgcn_exp2f(s[2 * i]);
                    float e1 = __builtin_amdgcn_exp2f(s[2 * i + 1]);
                    unsigned pm = pk2(e0, e1);
                    const unsigned mv = mdw[mbK * 4 + (i >> 1)];
                    const unsigned am = __builtin_amdgcn_perm(
                        mv, mv, (i & 1) ? 0x03030202u : 0x01010000u);
                    pm &= am;                      // masked key -> bf16 +0.0
                    pd[i] = pm;
                    float lo = __builtin_bit_cast(float, pm << 16);
                    float hi = __builtin_bit_cast(float, pm & 0xFFFF0000u);
                    lacc += lo + hi;               // l consistent with bf16 P
                }
                if (nb) l1 += lacc; else l0 += lacc;

                // P to wave-private LDS: keys mbK*32 + 8*g4 + 4*h6 + {0..3}
                char* prow = Ps + (nb * 32 + L5) * 144 + mbK * 64 + h6 * 8;
#pragma unroll
                for (int g4 = 0; g4 < 4; ++g4) {
                    uint2 t; t.x = pd[2 * g4]; t.y = pd[2 * g4 + 1];
                    *(uint2*)(prow + g4 * 16) = t;
                }
            }
        }

        // wave-private P just written; drain LDS before fragment reads
        __builtin_amdgcn_s_waitcnt(0xc07f);   // lgkmcnt(0)

        // ---- O^T += V^T * P^T ----
        short8 pf[2][4];
#pragma unroll
        for (int nb = 0; nb < 2; ++nb)
#pragma unroll
            for (int ks = 0; ks < 4; ++ks)
                pf[nb][ks] = *(const short8*)(Ps + (nb * 32 + L5) * 144 + ks * 32 + h6 * 16);
#pragma unroll
        for (int mbV = 0; mbV < 2; ++mbV) {
            short8 vf[4];
#pragma unroll
            for (int ks = 0; ks < 4; ++ks)
                vf[ks] = *(const short8*)(smem + 9216 + (mbV * 32 + L5) * 144 + ks * 32 + h6 * 16);
#pragma unroll
            for (int nb = 0; nb < 2; ++nb)
#pragma unroll
                for (int ks = 0; ks < 4; ++ks)
                    acc[mbV][nb] = __builtin_amdgcn_mfma_f32_32x32x16_bf16(
                        vf[ks], pf[nb][ks], acc[mbV][nb], 0, 0, 0);
        }
    }

    // ---- epilogue: l-reduce across h6 halves, LDS transpose, store ----
    l0 += __shfl_xor(l0, 32, 64);
    l1 += __shfl_xor(l1, 32, 64);
    const float inv[2] = {1.0f / l0, 1.0f / l1};
    __syncthreads();   // done with Ks/Vt/P everywhere; reuse Ps as fp32 tile
#pragma unroll
    for (int nb = 0; nb < 2; ++nb) {
#pragma unroll
        for (int mb = 0; mb < 2; ++mb)
#pragma unroll
            for (int g4 = 0; g4 < 4; ++g4) {
                float4 t;
                t.x = acc[mb][nb][g4 * 4 + 0] * inv[nb];
                t.y = acc[mb][nb][g4 * 4 + 1] * inv[nb];
                t.z = acc[mb][nb][g4 * 4 + 2] * inv[nb];
                t.w = acc[mb][nb][g4 * 4 + 3] * inv[nb];
                *(float4*)(Ps + (L5 * 68 + mb * 32 + g4 * 8 + h6 * 4) * 4) = t;
            }
        __builtin_amdgcn_s_waitcnt(0xc07f);   // lgkmcnt(0): writes done
        const int r16 = lane >> 4, dc = lane & 15;
#pragma unroll
        for (int i = 0; i < 8; ++i) {
            const int row = i * 4 + r16;
            float4 t = *(const float4*)(Ps + (row * 68 + dc * 4) * 4);
            *(float4*)(O + ((size_t)b * S + q0w + nb * 32 + row) * E + h * 64 + dc * 4) = t;
        }
        __builtin_amdgcn_s_waitcnt(0xc07f);   // reads done before nb=1 overwrites
    }
}

// ---------------- fallback (round-1 fp32 kernel, known-correct) ----------------
constexpr int QT = 64, KT = 64, LD = D + 4;
constexpr float SCALE = 0.125f;
__global__ __launch_bounds__(256, 3)
void fa_fp32(const float* __restrict__ Q, const float* __restrict__ K,
             const float* __restrict__ V, const int* __restrict__ M,
             float* __restrict__ Out)
{
    __shared__ float Qs[QT][LD];
    __shared__ float Vs[KT][LD];
    __shared__ float KPs[KT][LD];
    const int tid = threadIdx.x, tx = tid & 15, ty = tid >> 4;
    const int bid = blockIdx.x;
    const int h = bid % H, b = (bid / H) % B, qt = bid / (H * B);
    const int q0 = qt * QT;
    {
        const int col = tx * 4;
#pragma unroll
        for (int i = 0; i < 4; ++i) {
            const int row = ty + i * 16;
            *(float4*)&Qs[row][col] = *(const float4*)&Q[((size_t)(b * S + q0 + row)) * E + h * D + col];
        }
    }
    const int qr0 = ty * 4, d0 = tx * 4;
    float acc[4][4] = {};
    float m_i[4], l_i[4];
#pragma unroll
    for (int j = 0; j < 4; ++j) { m_i[j] = -INFINITY; l_i[j] = 0.0f; }
    for (int kt = 0; kt < S; kt += KT) {
        __syncthreads();
        {
            const int col = tx * 4;
#pragma unroll
            for (int i = 0; i < 4; ++i) {
                const int row = ty + i * 16;
                const size_t g = ((size_t)(b * S + kt + row)) * E + h * D + col;
                *(float4*)&KPs[row][col] = *(const float4*)&K[g];
                *(float4*)&Vs[row][col] = *(const float4*)&V[g];
            }
        }
        __syncthreads();
        float s[4][4] = {};
#pragma unroll
        for (int d = 0; d < D; d += 4) {
            float4 a[4], bb[4];
#pragma unroll
            for (int j = 0; j < 4; ++j) a[j] = *(const float4*)&Qs[qr0 + j][d];
#pragma unroll
            for (int i = 0; i < 4; ++i) bb[i] = *(const float4*)&KPs[tx + 16 * i][d];
#pragma unroll
            for (int j = 0; j < 4; ++j)
#pragma unroll
                for (int i = 0; i < 4; ++i)
                    s[j][i] += a[j].x * bb[i].x + a[j].y * bb[i].y + a[j].z * bb[i].z + a[j].w * bb[i].w;
        }
#pragma unroll
        for (int j = 0; j < 4; ++j) {
            const int* mrow = &M[((size_t)b * S + (q0 + qr0 + j)) * S + kt];
#pragma unroll
            for (int i = 0; i < 4; ++i) {
                const int mk = mrow[tx + 16 * i];
                s[j][i] = mk ? s[j][i] * SCALE : NEGF;
            }
        }
#pragma unroll
        for (int j = 0; j < 4; ++j) {
            float tm = fmaxf(fmaxf(s[j][0], s[j][1]), fmaxf(s[j][2], s[j][3]));
#pragma unroll
            for (int off = 8; off; off >>= 1) tm = fmaxf(tm, __shfl_xor(tm, off, 16));
            const float nm = fmaxf(m_i[j], tm);
            const float alpha = __expf(m_i[j] - nm);
            m_i[j] = nm;
            float rs = 0.0f;
#pragma unroll
            for (int i = 0; i < 4; ++i) { const float p = __expf(s[j][i] - nm); s[j][i] = p; rs += p; }
#pragma unroll
            for (int off = 8; off; off >>= 1) rs += __shfl_xor(rs, off, 16);
            l_i[j] = l_i[j] * alpha + rs;
#pragma unroll
            for (int dd = 0; dd < 4; ++dd) acc[j][dd] *= alpha;
        }
        __syncthreads();
#pragma unroll
        for (int j = 0; j < 4; ++j)
#pragma unroll
            for (int i = 0; i < 4; ++i) KPs[qr0 + j][tx + 16 * i] = s[j][i];
        __syncthreads();
#pragma unroll 4
        for (int kk = 0; kk < KT; kk += 4) {
            float4 p[4], vv[4];
#pragma unroll
            for (int j = 0; j < 4; ++j) p[j] = *(const float4*)&KPs[qr0 + j][kk];
#pragma unroll
            for (int u = 0; u < 4; ++u) vv[u] = *(const float4*)&Vs[kk + u][d0];
#pragma unroll
            for (int j = 0; j < 4; ++j) {
                acc[j][0] += p[j].x * vv[0].x + p[j].y * vv[1].x + p[j].z * vv[2].x + p[j].w * vv[3].x;
                acc[j][1] += p[j].x * vv[0].y + p[j].y * vv[1].y + p[j].z * vv[2].y + p[j].w * vv[3].y;
                acc[j][2] += p[j].x * vv[0].z + p[j].y * vv[1].z + p[j].z * vv[2].z + p[j].w * vv[3].z;
                acc[j][3] += p[j].x * vv[0].w + p[j].y * vv[1].w + p[j].z * vv[2].w + p[j].w * vv[3].w;
            }
        }
    }
#pragma unroll
    for (int j = 0; j < 4; ++j) {
        const float iv = 1.0f / l_i[j];
        float4 r;
        r.x = acc[j][0] * iv; r.y = acc[j][1] * iv; r.z = acc[j][2] * iv; r.w = acc[j][3] * iv;
        *(float4*)&Out[((size_t)(b * S + q0 + qr0 + j)) * E + h * D + d0] = r;
    }
}

extern "C" void kernel_launch(void* const* d_in, const int* in_sizes, int n_in,
                              void* d_out, int out_size, void* d_ws, size_t ws_size,
                              hipStream_t stream) {
    (void)in_sizes; (void)n_in; (void)out_size;
    const float* q = (const float*)d_in[0];
    const float* k = (const float*)d_in[1];
    const float* v = (const float*)d_in[2];
    const int*   m = (const int*)d_in[3];
    float* out = (float*)d_out;

    if (ws_size >= WS_NEED) {
        char* ws = (char*)d_ws;
        prep_all<<<2048, 256, 0, stream>>>(k, v, m, ws);
        fa_mfma<<<512, 256, 0, stream>>>(q, ws, out);
    } else {
        fa_fp32<<<B * H * (S / QT), 256, 0, stream>>>(q, k, v, m, out);
    }
}